// Round 2
// baseline (6605.283 us; speedup 1.0000x reference)
//
#include <hip/hip_runtime.h>
#include <math.h>

#define NVOX 250000
#define NPART 125000
#define NPTS 600000
#define NNEXT 100000
#define NDS 100000
#define NCELL 1382400

static __device__ __forceinline__ float lk(float x) { return x >= 0.f ? x : 0.1f * x; }

// ---------------- fill ----------------
__global__ void fill_u32_kernel(unsigned* __restrict__ p, unsigned v, long n) {
    long i = (long)blockIdx.x * 256 + threadIdx.x;
    if (i < n) p[i] = v;
}

// ---------------- submanifold conv: Y[n,d] = sum_k sum_c X[nbr[n,k],c] * W[k,c,d] ----------------
// 64 rows x 64 cols per block, 256 threads, 4x4 register tile per thread.
__global__ __launch_bounds__(256) void subm_conv_kernel(
    const float* __restrict__ X, const int* __restrict__ nbr,
    const float* __restrict__ W, float* __restrict__ Y, int N)
{
    __shared__ float XsT[64][68];   // [c][r], padded
    __shared__ float Ws[64][68];    // [c][d], padded
    const int t = threadIdx.x;
    const int row0 = blockIdx.x * 64;
    const int ty = t >> 4, tx = t & 15;
    const int lr = t >> 2, ls = t & 3;
    const int grow = row0 + lr;
    const bool lv = grow < N;
    float acc[4][4] = {{0.f}};

    for (int k = 0; k < 27; ++k) {
        const float* Wk = W + k * 4096;
        float4 w0 = *(const float4*)(Wk + t * 4);
        float4 w1 = *(const float4*)(Wk + t * 4 + 1024);
        float4 w2 = *(const float4*)(Wk + t * 4 + 2048);
        float4 w3 = *(const float4*)(Wk + t * 4 + 3072);
        int j = lv ? nbr[grow * 27 + k] : 0;
        const float* xr = X + (size_t)j * 64 + ls * 16;
        float4 v0 = *(const float4*)(xr);
        float4 v1 = *(const float4*)(xr + 4);
        float4 v2 = *(const float4*)(xr + 8);
        float4 v3 = *(const float4*)(xr + 12);
        __syncthreads();   // prior compute done before LDS overwrite
        {
            int i0 = t * 4;
            *(float4*)&Ws[i0 >> 6][i0 & 63] = w0; i0 += 1024;
            *(float4*)&Ws[i0 >> 6][i0 & 63] = w1; i0 += 1024;
            *(float4*)&Ws[i0 >> 6][i0 & 63] = w2; i0 += 1024;
            *(float4*)&Ws[i0 >> 6][i0 & 63] = w3;
        }
        const int cb = ls * 16;
        XsT[cb + 0][lr] = v0.x; XsT[cb + 1][lr] = v0.y; XsT[cb + 2][lr] = v0.z; XsT[cb + 3][lr] = v0.w;
        XsT[cb + 4][lr] = v1.x; XsT[cb + 5][lr] = v1.y; XsT[cb + 6][lr] = v1.z; XsT[cb + 7][lr] = v1.w;
        XsT[cb + 8][lr] = v2.x; XsT[cb + 9][lr] = v2.y; XsT[cb + 10][lr] = v2.z; XsT[cb + 11][lr] = v2.w;
        XsT[cb + 12][lr] = v3.x; XsT[cb + 13][lr] = v3.y; XsT[cb + 14][lr] = v3.z; XsT[cb + 15][lr] = v3.w;
        __syncthreads();
        #pragma unroll 16
        for (int c = 0; c < 64; ++c) {
            float4 xv = *(const float4*)&XsT[c][ty * 4];
            float4 wv = *(const float4*)&Ws[c][tx * 4];
            acc[0][0] += xv.x * wv.x; acc[0][1] += xv.x * wv.y; acc[0][2] += xv.x * wv.z; acc[0][3] += xv.x * wv.w;
            acc[1][0] += xv.y * wv.x; acc[1][1] += xv.y * wv.y; acc[1][2] += xv.y * wv.z; acc[1][3] += xv.y * wv.w;
            acc[2][0] += xv.z * wv.x; acc[2][1] += xv.z * wv.y; acc[2][2] += xv.z * wv.z; acc[2][3] += xv.z * wv.w;
            acc[3][0] += xv.w * wv.x; acc[3][1] += xv.w * wv.y; acc[3][2] += xv.w * wv.z; acc[3][3] += xv.w * wv.w;
        }
    }
    #pragma unroll
    for (int i2 = 0; i2 < 4; ++i2) {
        int r = row0 + ty * 4 + i2;
        if (r < N)
            *(float4*)(Y + (size_t)r * 64 + tx * 4) =
                make_float4(acc[i2][0], acc[i2][1], acc[i2][2], acc[i2][3]);
    }
}

// ---------------- per-column sum / sumsq ----------------
template<int CC>
__global__ __launch_bounds__(256) void colstats_kernel(const float* __restrict__ Y, int N, float* __restrict__ stats) {
    constexpr int RG = 256 / CC;
    const int t = threadIdx.x;
    const int c = t % CC, rg = t / CC;
    float s = 0.f, s2 = 0.f;
    for (long r = (long)blockIdx.x * RG + rg; r < N; r += (long)gridDim.x * RG) {
        float v = Y[r * CC + c];
        s += v; s2 += v * v;
    }
    __shared__ float sh[256], sh2[256];
    sh[t] = s; sh2[t] = s2;
    __syncthreads();
    if (t < CC) {
        #pragma unroll
        for (int g = 1; g < RG; ++g) { s += sh[g * CC + t]; s2 += sh2[g * CC + t]; }
        atomicAdd(&stats[t], s);
        atomicAdd(&stats[CC + t], s2);
    }
}

__global__ void mkscale_kernel(float* __restrict__ stats, const float* __restrict__ g,
                               const float* __restrict__ b, float invN, int CC) {
    int c = threadIdx.x;
    if (c < CC) {
        float mu = stats[c] * invN;
        float var = stats[CC + c] * invN - mu * mu;
        float sc = g[c] * rsqrtf(var + 1e-5f);
        stats[2 * CC + c] = sc;
        stats[3 * CC + c] = b[c] - mu * sc;
    }
}

// MODE: 0 = y*s+sh ; 1 = leaky(y*s+sh) ; 2 = leaky(y*s+sh + res) ; 3 = res2 + leaky(y*s+sh + res)
template<int CC, int MODE>
__global__ __launch_bounds__(256) void apply_bn_kernel(
    const float* __restrict__ Yin, const float* __restrict__ stats,
    const float* __restrict__ res, const float* __restrict__ res2,
    float* __restrict__ out, long n4)
{
    long i = (long)blockIdx.x * 256 + threadIdx.x;
    if (i >= n4) return;
    int c4 = (int)(i % (CC / 4)) * 4;
    float4 y = ((const float4*)Yin)[i];
    float4 sc = *(const float4*)(stats + 2 * CC + c4);
    float4 sf = *(const float4*)(stats + 3 * CC + c4);
    float x0 = y.x * sc.x + sf.x;
    float x1 = y.y * sc.y + sf.y;
    float x2 = y.z * sc.z + sf.z;
    float x3 = y.w * sc.w + sf.w;
    if (MODE >= 2) {
        float4 rr = ((const float4*)res)[i];
        x0 += rr.x; x1 += rr.y; x2 += rr.z; x3 += rr.w;
    }
    if (MODE >= 1) { x0 = lk(x0); x1 = lk(x1); x2 = lk(x2); x3 = lk(x3); }
    if (MODE == 3) {
        float4 rr2 = ((const float4*)res2)[i];
        x0 += rr2.x; x1 += rr2.y; x2 += rr2.z; x3 += rr2.w;
    }
    ((float4*)out)[i] = make_float4(x0, x1, x2, x3);
}

// ---------------- generic tiled GEMM: Y = act(X[N,CIN] @ W[CIN,COUT] + bias) ----------------
template<int CIN, int COUT, int ACT>
__global__ __launch_bounds__(256) void gemm_kernel(
    const float* __restrict__ X, const float* __restrict__ W,
    const float* __restrict__ bias, float* __restrict__ Y, int N)
{
    constexpr int TX = COUT / 4;
    constexpr int TY = 256 / TX;
    constexpr int ROWS = TY * 4;
    constexpr int CHUNK = (CIN < 64) ? CIN : 64;
    constexpr int NCH = CIN / CHUNK;
    __shared__ float XsT[CHUNK][ROWS + 4];
    __shared__ float Ws[CHUNK][COUT + 4];
    const int t = threadIdx.x;
    const int row0 = blockIdx.x * ROWS;
    const int ty = t / TX, tx = t % TX;
    float acc[4][4] = {{0.f}};
    for (int cc = 0; cc < NCH; ++cc) {
        __syncthreads();
        for (int i = t * 4; i < CHUNK * COUT; i += 1024) {
            int c = i / COUT, d = i % COUT;
            *(float4*)&Ws[c][d] = *(const float4*)(W + (size_t)(cc * CHUNK + c) * COUT + d);
        }
        for (int i = t * 4; i < ROWS * CHUNK; i += 1024) {
            int r = i / CHUNK, c0 = i % CHUNK;
            int gr = row0 + r;
            float4 v = make_float4(0.f, 0.f, 0.f, 0.f);
            if (gr < N) v = *(const float4*)(X + (size_t)gr * CIN + cc * CHUNK + c0);
            XsT[c0 + 0][r] = v.x; XsT[c0 + 1][r] = v.y; XsT[c0 + 2][r] = v.z; XsT[c0 + 3][r] = v.w;
        }
        __syncthreads();
        #pragma unroll 8
        for (int c = 0; c < CHUNK; ++c) {
            float4 xv = *(const float4*)&XsT[c][ty * 4];
            float4 wv = *(const float4*)&Ws[c][tx * 4];
            acc[0][0] += xv.x * wv.x; acc[0][1] += xv.x * wv.y; acc[0][2] += xv.x * wv.z; acc[0][3] += xv.x * wv.w;
            acc[1][0] += xv.y * wv.x; acc[1][1] += xv.y * wv.y; acc[1][2] += xv.y * wv.z; acc[1][3] += xv.y * wv.w;
            acc[2][0] += xv.z * wv.x; acc[2][1] += xv.z * wv.y; acc[2][2] += xv.z * wv.z; acc[2][3] += xv.z * wv.w;
            acc[3][0] += xv.w * wv.x; acc[3][1] += xv.w * wv.y; acc[3][2] += xv.w * wv.z; acc[3][3] += xv.w * wv.w;
        }
    }
    float4 bv = *(const float4*)(bias + tx * 4);
    #pragma unroll
    for (int i2 = 0; i2 < 4; ++i2) {
        int gr = row0 + ty * 4 + i2;
        if (gr < N) {
            float o0 = acc[i2][0] + bv.x, o1 = acc[i2][1] + bv.y;
            float o2 = acc[i2][2] + bv.z, o3 = acc[i2][3] + bv.w;
            if (ACT) { o0 = lk(o0); o1 = lk(o1); o2 = lk(o2); o3 = lk(o3); }
            *(float4*)(Y + (size_t)gr * COUT + tx * 4) = make_float4(o0, o1, o2, o3);
        }
    }
}

// ---------------- fused layer_out:
// T = leaky(cat[cil] @ Wo1 + bo1)  (cat = [identity | h3[dsinv]], never materialized)
// U = T @ Wo2 + bo2 ; psum[cin[r]] += U[r] ; pcnt[cin[r]] += 1
__global__ __launch_bounds__(256) void layer_out_fused_kernel(
    const float* __restrict__ iden, const float* __restrict__ h3,
    const int* __restrict__ cil, const int* __restrict__ dsinv,
    const float* __restrict__ Wo1, const float* __restrict__ bo1,
    const float* __restrict__ Wo2, const float* __restrict__ bo2,
    const int* __restrict__ cin,
    float* __restrict__ psum, float* __restrict__ pcnt, int N)
{
    __shared__ float XsT[64][68];
    __shared__ float Ws[64][68];
    const int t = threadIdx.x;
    const int row0 = blockIdx.x * 64;
    const int ty = t >> 4, tx = t & 15;
    const int lr = t >> 2, ls = t & 3;
    const int gr = row0 + lr;
    int v = (gr < N) ? cil[gr] : 0;
    int vds = dsinv[v];
    float acc[4][4] = {{0.f}};
    // ---- stage 1: T tile in acc ----
    for (int cc = 0; cc < 2; ++cc) {
        const float* src = (cc == 0) ? (iden + (size_t)v * 64) : (h3 + (size_t)vds * 64);
        const float* xr = src + ls * 16;
        float4 v0 = *(const float4*)(xr);
        float4 v1 = *(const float4*)(xr + 4);
        float4 v2f = *(const float4*)(xr + 8);
        float4 v3 = *(const float4*)(xr + 12);
        const float* Wk = Wo1 + (size_t)cc * 4096;
        float4 w0 = *(const float4*)(Wk + t * 4);
        float4 w1 = *(const float4*)(Wk + t * 4 + 1024);
        float4 w2 = *(const float4*)(Wk + t * 4 + 2048);
        float4 w3 = *(const float4*)(Wk + t * 4 + 3072);
        __syncthreads();
        {
            int i0 = t * 4;
            *(float4*)&Ws[i0 >> 6][i0 & 63] = w0; i0 += 1024;
            *(float4*)&Ws[i0 >> 6][i0 & 63] = w1; i0 += 1024;
            *(float4*)&Ws[i0 >> 6][i0 & 63] = w2; i0 += 1024;
            *(float4*)&Ws[i0 >> 6][i0 & 63] = w3;
        }
        const int cb = ls * 16;
        XsT[cb + 0][lr] = v0.x; XsT[cb + 1][lr] = v0.y; XsT[cb + 2][lr] = v0.z; XsT[cb + 3][lr] = v0.w;
        XsT[cb + 4][lr] = v1.x; XsT[cb + 5][lr] = v1.y; XsT[cb + 6][lr] = v1.z; XsT[cb + 7][lr] = v1.w;
        XsT[cb + 8][lr] = v2f.x; XsT[cb + 9][lr] = v2f.y; XsT[cb + 10][lr] = v2f.z; XsT[cb + 11][lr] = v2f.w;
        XsT[cb + 12][lr] = v3.x; XsT[cb + 13][lr] = v3.y; XsT[cb + 14][lr] = v3.z; XsT[cb + 15][lr] = v3.w;
        __syncthreads();
        #pragma unroll 16
        for (int c = 0; c < 64; ++c) {
            float4 xv = *(const float4*)&XsT[c][ty * 4];
            float4 wv = *(const float4*)&Ws[c][tx * 4];
            acc[0][0] += xv.x * wv.x; acc[0][1] += xv.x * wv.y; acc[0][2] += xv.x * wv.z; acc[0][3] += xv.x * wv.w;
            acc[1][0] += xv.y * wv.x; acc[1][1] += xv.y * wv.y; acc[1][2] += xv.y * wv.z; acc[1][3] += xv.y * wv.w;
            acc[2][0] += xv.z * wv.x; acc[2][1] += xv.z * wv.y; acc[2][2] += xv.z * wv.z; acc[2][3] += xv.z * wv.w;
            acc[3][0] += xv.w * wv.x; acc[3][1] += xv.w * wv.y; acc[3][2] += xv.w * wv.z; acc[3][3] += xv.w * wv.w;
        }
    }
    // ---- stage 2: T^T -> LDS, Wo2 -> LDS ----
    float4 u0 = *(const float4*)(Wo2 + t * 4);
    float4 u1 = *(const float4*)(Wo2 + t * 4 + 1024);
    float4 u2 = *(const float4*)(Wo2 + t * 4 + 2048);
    float4 u3 = *(const float4*)(Wo2 + t * 4 + 3072);
    float4 b1v = *(const float4*)(bo1 + tx * 4);
    __syncthreads();   // stage-1 LDS reads done
    {
        int i0 = t * 4;
        *(float4*)&Ws[i0 >> 6][i0 & 63] = u0; i0 += 1024;
        *(float4*)&Ws[i0 >> 6][i0 & 63] = u1; i0 += 1024;
        *(float4*)&Ws[i0 >> 6][i0 & 63] = u2; i0 += 1024;
        *(float4*)&Ws[i0 >> 6][i0 & 63] = u3;
    }
    #pragma unroll
    for (int i = 0; i < 4; ++i) {
        XsT[tx * 4 + 0][ty * 4 + i] = lk(acc[i][0] + b1v.x);
        XsT[tx * 4 + 1][ty * 4 + i] = lk(acc[i][1] + b1v.y);
        XsT[tx * 4 + 2][ty * 4 + i] = lk(acc[i][2] + b1v.z);
        XsT[tx * 4 + 3][ty * 4 + i] = lk(acc[i][3] + b1v.w);
    }
    __syncthreads();
    // ---- stage 3: U = T @ Wo2 ----
    float acc2[4][4] = {{0.f}};
    #pragma unroll 16
    for (int c = 0; c < 64; ++c) {
        float4 xv = *(const float4*)&XsT[c][ty * 4];
        float4 wv = *(const float4*)&Ws[c][tx * 4];
        acc2[0][0] += xv.x * wv.x; acc2[0][1] += xv.x * wv.y; acc2[0][2] += xv.x * wv.z; acc2[0][3] += xv.x * wv.w;
        acc2[1][0] += xv.y * wv.x; acc2[1][1] += xv.y * wv.y; acc2[1][2] += xv.y * wv.z; acc2[1][3] += xv.y * wv.w;
        acc2[2][0] += xv.z * wv.x; acc2[2][1] += xv.z * wv.y; acc2[2][2] += xv.z * wv.z; acc2[2][3] += xv.z * wv.w;
        acc2[3][0] += xv.w * wv.x; acc2[3][1] += xv.w * wv.y; acc2[3][2] += xv.w * wv.z; acc2[3][3] += xv.w * wv.w;
    }
    // ---- stage 4: scatter-add ----
    float4 b2v = *(const float4*)(bo2 + tx * 4);
    #pragma unroll
    for (int i2 = 0; i2 < 4; ++i2) {
        int gr2 = row0 + ty * 4 + i2;
        if (gr2 < N) {
            int tg = cin[gr2];
            float* dst = psum + (size_t)tg * 64 + tx * 4;
            atomicAdd(dst + 0, acc2[i2][0] + b2v.x);
            atomicAdd(dst + 1, acc2[i2][1] + b2v.y);
            atomicAdd(dst + 2, acc2[i2][2] + b2v.z);
            atomicAdd(dst + 3, acc2[i2][3] + b2v.w);
            if (tx == 0) atomicAdd(pcnt + tg, 1.0f);
        }
    }
}

// ---------------- scatter add (segment sum) ----------------
__global__ void scatter_add_kernel(const float* __restrict__ X, const int* __restrict__ idx,
                                   float* __restrict__ sum, float* __restrict__ cnt, long N) {
    long i = (long)blockIdx.x * 256 + threadIdx.x;
    if (i < N * 64) {
        long n = i >> 6; int c = (int)(i & 63);
        int tg = idx[n];
        atomicAdd(&sum[(size_t)tg * 64 + c], X[i]);
        if (c == 0) atomicAdd(&cnt[tg], 1.0f);
    }
}

__global__ void divcnt_kernel(float* __restrict__ sum, const float* __restrict__ cnt, long total) {
    long i = (long)blockIdx.x * 256 + threadIdx.x;
    if (i < total) sum[i] /= fmaxf(cnt[i >> 6], 1.0f);
}

__global__ void gather_out_kernel(const float* __restrict__ pf, const int* __restrict__ cin,
                                  float* __restrict__ out, int N) {
    long i = (long)blockIdx.x * 256 + threadIdx.x;
    if (i < (long)N * 16) {
        int p = (int)(i >> 4), q = (int)(i & 15);
        ((float4*)out)[i] = *(const float4*)(pf + (size_t)cin[p] * 64 + q * 4);
    }
}

// ---------------- logit conv: 1 wave per row, lane = channel ----------------
__global__ __launch_bounds__(256) void logit_kernel(
    const float* __restrict__ vp, const int* __restrict__ nbrp,
    const float* __restrict__ Wlog, const float* __restrict__ blog,
    float* __restrict__ out, int N)
{
    __shared__ float Wl[27 * 64];
    const int t = threadIdx.x;
    for (int i = t; i < 1728; i += 256) Wl[i] = Wlog[i];
    __syncthreads();
    const int wave = t >> 6, lane = t & 63;
    for (long row = (long)blockIdx.x * 4 + wave; row < N; row += (long)gridDim.x * 4) {
        float acc = 0.f;
        #pragma unroll
        for (int k = 0; k < 27; ++k) {
            int j = nbrp[row * 27 + k];
            acc += vp[(size_t)j * 64 + lane] * Wl[k * 64 + lane];
        }
        for (int off = 32; off > 0; off >>= 1) acc += __shfl_down(acc, off, 64);
        if (lane == 0) out[row] = acc + blog[0];
    }
}

// ---------------- loss ----------------
__global__ void loss_scatter1_kernel(const int* __restrict__ coors, int* __restrict__ tflag,
                                     int* __restrict__ winner, int N, int NP) {
    int n = blockIdx.x * 256 + threadIdx.x;
    if (n < N) {
        int b = coors[n * 4], x = coors[n * 4 + 1], y = coors[n * 4 + 2], z = coors[n * 4 + 3];
        int flat = ((b * 240 + x) * 180 + y) * 16 + z;
        tflag[flat] = 1;
        if (n < NP) atomicMax(&winner[flat], n);   // numpy x[idx]=v: last occurrence wins
    }
}

__global__ void loss_scatter2_kernel(const int* __restrict__ coors, const int* __restrict__ winner,
                                     const float* __restrict__ logit, float* __restrict__ xdense, int NP) {
    int n = blockIdx.x * 256 + threadIdx.x;
    if (n < NP) {
        int b = coors[n * 4], x = coors[n * 4 + 1], y = coors[n * 4 + 2], z = coors[n * 4 + 3];
        int flat = ((b * 240 + x) * 180 + y) * 16 + z;
        if (winner[flat] == n) xdense[flat] = logit[n];
    }
}

__global__ void loss_reduce_kernel(const float* __restrict__ xdense, const int* __restrict__ tflag,
                                   float* __restrict__ accum) {
    int i = blockIdx.x * 256 + threadIdx.x;
    float x = xdense[i];
    float tt = (float)tflag[i];
    float term = fmaxf(x, 0.f) - x * tt + log1pf(expf(-fabsf(x)));
    __shared__ float sh[256];
    sh[threadIdx.x] = term;
    __syncthreads();
    for (int s = 128; s > 0; s >>= 1) {
        if (threadIdx.x < s) sh[threadIdx.x] += sh[threadIdx.x + s];
        __syncthreads();
    }
    if (threadIdx.x == 0) atomicAdd(accum, sh[0]);
}

__global__ void loss_final_kernel(const float* __restrict__ accum, float* __restrict__ out) {
    out[0] = accum[0] / (float)NCELL;
}

// ---------------- host orchestration ----------------
extern "C" void kernel_launch(void* const* d_in, const int* in_sizes, int n_in,
                              void* d_out, int out_size, void* d_ws, size_t ws_size,
                              hipStream_t stream)
{
    const float* feats  = (const float*)d_in[0];
    const float* featsp = (const float*)d_in[1];
    const float* Wv11 = (const float*)d_in[2];
    const float* Wv12 = (const float*)d_in[3];
    const float* Wv21 = (const float*)d_in[4];
    const float* Wv22 = (const float*)d_in[5];
    const float* g11 = (const float*)d_in[6];
    const float* g12 = (const float*)d_in[7];
    const float* g21 = (const float*)d_in[8];
    const float* g22 = (const float*)d_in[9];
    const float* b11 = (const float*)d_in[10];
    const float* b12 = (const float*)d_in[11];
    const float* b21 = (const float*)d_in[12];
    const float* b22 = (const float*)d_in[13];
    const float* Wlog = (const float*)d_in[14];
    const float* blog = (const float*)d_in[15];
    const float* Wi  = (const float*)d_in[16];
    const float* bi  = (const float*)d_in[17];
    const float* Wp1 = (const float*)d_in[18];
    const float* bp1 = (const float*)d_in[19];
    const float* gp1 = (const float*)d_in[20];
    const float* bp1n = (const float*)d_in[21];
    const float* Wp2 = (const float*)d_in[22];
    const float* bp2 = (const float*)d_in[23];
    const float* gp2 = (const float*)d_in[24];
    const float* bp2n = (const float*)d_in[25];
    const float* Wp3 = (const float*)d_in[26];
    const float* bp3 = (const float*)d_in[27];
    const float* Wo1 = (const float*)d_in[28];
    const float* bo1 = (const float*)d_in[29];
    const float* Wo2 = (const float*)d_in[30];
    const float* bo2 = (const float*)d_in[31];
    const int* nbr   = (const int*)d_in[32];
    const int* nbrp  = (const int*)d_in[33];
    const int* coors = (const int*)d_in[34];
    const int* cil   = (const int*)d_in[35];
    const int* cin   = (const int*)d_in[36];
    const int* dsinv = (const int*)d_in[37];
    (void)in_sizes; (void)n_in; (void)out_size; (void)ws_size;

    // ---- workspace layout (48,002,561 floats = 192.0 MB total) ----
    float* ws = (float*)d_ws;
    float* A    = ws;                 // 16M : conv scratch -> Cp(partial) -> identity
    float* H    = ws + 16000000L;     // 16M : h -> X1 -> feat_sum
    float* Cb   = ws + 32000000L;     // 16M : h2 -> {Ap,Hp} -> {psum,pcnt}
    float* Ap   = Cb;                 //  8M  partial conv scratch
    float* Hp   = ws + 40000000L;     //  8M  partial h / X1
    float* Cp   = A;                  //  8M  partial V (before identity gemm)
    float* psum = Cb;                 //  6.4M (after partial chain done)
    float* pcnt = ws + 38400000L;     //  0.1M
    float* stats = ws + 48000000L;    //  10 x 256
    float* lacc  = ws + 48002560L;    //  1

    // ---- d_out used as scratch (fully overwritten by final gather) ----
    float* o = (float*)d_out;
    float* dssum  = o;                        // 6.4M
    float* t1b    = o + 6400000L;             // 3.2M
    float* t2b    = o + 9600000L;             // 3.2M
    float* h3b    = o + 12800000L;            // 6.4M
    float* logitb = o + 19200000L;            // 125k
    float* xdense = o + 19328000L;            // 1.3824M
    int*   tflag  = (int*)(o + 20710400L);    // 1.3824M
    int*   winner = (int*)(o + 22092800L);    // 1.3824M
    float* dscnt  = o + 23475200L;            // 100k
    float* out = (float*)d_out;

    auto cdiv = [](long a, long b) { return (unsigned)((a + b - 1) / b); };
    dim3 B256(256);

    // ---- zero/flag inits ----
    fill_u32_kernel<<<cdiv(2561, 256), B256, 0, stream>>>((unsigned*)stats, 0u, 2561);                  // stats+lacc
    fill_u32_kernel<<<cdiv(6400000, 256), B256, 0, stream>>>((unsigned*)dssum, 0u, 6400000);            // dssum
    fill_u32_kernel<<<cdiv(100000, 256), B256, 0, stream>>>((unsigned*)dscnt, 0u, 100000);              // dscnt
    fill_u32_kernel<<<cdiv(2764800, 256), B256, 0, stream>>>((unsigned*)xdense, 0u, 2764800);           // xdense+tflag
    fill_u32_kernel<<<cdiv(1382400, 256), B256, 0, stream>>>((unsigned*)winner, 0xFFFFFFFFu, 1382400);  // winner = -1

    auto conv_stage = [&](const float* xin, const int* nb, const float* Wv,
                          const float* g, const float* b, int N, int stage,
                          const float* res, const float* res2,
                          float* convbuf, float* outbuf, int mode) {
        subm_conv_kernel<<<cdiv(N, 64), B256, 0, stream>>>(xin, nb, Wv, convbuf, N);
        colstats_kernel<64><<<256, B256, 0, stream>>>(convbuf, N, stats + stage * 256);
        mkscale_kernel<<<1, 64, 0, stream>>>(stats + stage * 256, g, b, 1.0f / (float)N, 64);
        long n4 = (long)N * 16;
        float* st = stats + stage * 256;
        if (mode == 1)
            apply_bn_kernel<64, 1><<<cdiv(n4, 256), B256, 0, stream>>>(convbuf, st, nullptr, nullptr, outbuf, n4);
        else if (mode == 2)
            apply_bn_kernel<64, 2><<<cdiv(n4, 256), B256, 0, stream>>>(convbuf, st, res, nullptr, outbuf, n4);
        else
            apply_bn_kernel<64, 3><<<cdiv(n4, 256), B256, 0, stream>>>(convbuf, st, res, res2, outbuf, n4);
    };

    // ---- full tensor: v = bb2(bb1(feats)); H ends as feat_sum = feats + v ----
    conv_stage(feats, nbr, Wv11, g11, b11, NVOX, 0, nullptr, nullptr, A, H, 1);   // H = h
    conv_stage(H,     nbr, Wv12, g12, b12, NVOX, 1, feats, nullptr, A, H, 2);     // H = X1
    conv_stage(H,     nbr, Wv21, g21, b21, NVOX, 2, nullptr, nullptr, A, Cb, 1);  // Cb = h2
    conv_stage(Cb,    nbr, Wv22, g22, b22, NVOX, 3, H, feats, A, H, 3);           // H = feat_sum
    // ---- partial tensor: vp (same weights), buffers aliased into Cb/A ----
    conv_stage(featsp, nbrp, Wv11, g11, b11, NPART, 4, nullptr, nullptr, Ap, Hp, 1);
    conv_stage(Hp,     nbrp, Wv12, g12, b12, NPART, 5, featsp, nullptr, Ap, Hp, 2);
    conv_stage(Hp,     nbrp, Wv21, g21, b21, NPART, 6, nullptr, nullptr, Ap, Cp, 1);
    conv_stage(Cp,     nbrp, Wv22, g22, b22, NPART, 7, Hp, nullptr, Ap, Cp, 2);   // Cp = Vp

    // ---- logits + BCE loss ----
    logit_kernel<<<cdiv(NPART, 4), B256, 0, stream>>>(Cp, nbrp, Wlog, blog, logitb, NPART);
    // partial chain done -> psum/pcnt region (aliased over Ap) can be zeroed now
    fill_u32_kernel<<<cdiv(6500000, 256), B256, 0, stream>>>((unsigned*)psum, 0u, 6500000);
    loss_scatter1_kernel<<<cdiv(NVOX, 256), B256, 0, stream>>>(coors, tflag, winner, NVOX, NPART);
    loss_scatter2_kernel<<<cdiv(NPART, 256), B256, 0, stream>>>(coors, winner, logitb, xdense, NPART);
    loss_reduce_kernel<<<NCELL / 256, B256, 0, stream>>>(xdense, tflag, lacc);

    // ---- point encoder ----
    scatter_add_kernel<<<cdiv((long)NVOX * 64, 256), B256, 0, stream>>>(H, dsinv, dssum, dscnt, (long)NVOX);
    divcnt_kernel<<<cdiv((long)NDS * 64, 256), B256, 0, stream>>>(dssum, dscnt, (long)NDS * 64);  // dssum = ds
    gemm_kernel<64, 64, 1><<<cdiv(NVOX, 64), B256, 0, stream>>>(H, Wi, bi, A, NVOX);              // A = identity

    gemm_kernel<64, 32, 1><<<cdiv(NDS, 128), B256, 0, stream>>>(dssum, Wp1, bp1, t1b, NDS);
    colstats_kernel<32><<<256, B256, 0, stream>>>(t1b, NDS, stats + 8 * 256);
    mkscale_kernel<<<1, 64, 0, stream>>>(stats + 8 * 256, gp1, bp1n, 1.0f / (float)NDS, 32);
    apply_bn_kernel<32, 0><<<cdiv((long)NDS * 8, 256), B256, 0, stream>>>(t1b, stats + 8 * 256, nullptr, nullptr, t1b, (long)NDS * 8);

    gemm_kernel<32, 32, 1><<<cdiv(NDS, 128), B256, 0, stream>>>(t1b, Wp2, bp2, t2b, NDS);
    colstats_kernel<32><<<256, B256, 0, stream>>>(t2b, NDS, stats + 9 * 256);
    mkscale_kernel<<<1, 64, 0, stream>>>(stats + 9 * 256, gp2, bp2n, 1.0f / (float)NDS, 32);
    apply_bn_kernel<32, 0><<<cdiv((long)NDS * 8, 256), B256, 0, stream>>>(t2b, stats + 9 * 256, nullptr, nullptr, t2b, (long)NDS * 8);

    gemm_kernel<32, 64, 1><<<cdiv(NDS, 64), B256, 0, stream>>>(t2b, Wp3, bp3, h3b, NDS);

    // ---- fused layer_out + scatter-mean numerator ----
    layer_out_fused_kernel<<<cdiv(NPTS, 64), B256, 0, stream>>>(A, h3b, cil, dsinv, Wo1, bo1, Wo2, bo2, cin, psum, pcnt, NPTS);
    divcnt_kernel<<<cdiv((long)NNEXT * 64, 256), B256, 0, stream>>>(psum, pcnt, (long)NNEXT * 64);

    // ---- final outputs (overwrite all d_out scratch) ----
    gather_out_kernel<<<cdiv((long)NPTS * 16, 256), B256, 0, stream>>>(psum, cin, out, NPTS);
    loss_final_kernel<<<1, 1, 0, stream>>>(lacc, out + 38400000L);
}

// Round 3
// 5507.004 us; speedup vs baseline: 1.1994x; 1.1994x over previous
//
#include <hip/hip_runtime.h>
#include <math.h>

#define NVOX 250000
#define NPART 125000
#define NPTS 600000
#define NNEXT 100000
#define NDS 100000
#define NCELL 1382400

static __device__ __forceinline__ float lk(float x) { return x >= 0.f ? x : 0.1f * x; }

// bf16 helpers (RNE)
static __device__ __forceinline__ unsigned short f2bf(float f) {
    unsigned u = __float_as_uint(f);
    unsigned r = (u + 0x7FFFu + ((u >> 16) & 1u)) >> 16;
    return (unsigned short)r;
}
static __device__ __forceinline__ float bf2f(unsigned short h) {
    return __uint_as_float((unsigned)h << 16);
}

typedef short v8s __attribute__((ext_vector_type(8)));   // 8 bf16 = 4 VGPR
typedef float v4f __attribute__((ext_vector_type(4)));   // MFMA acc
#define MFMA16 __builtin_amdgcn_mfma_f32_16x16x32_bf16

// ---------------- fill ----------------
__global__ void fill_u32_kernel(unsigned* __restrict__ p, unsigned v, long n) {
    long i = (long)blockIdx.x * 256 + threadIdx.x;
    if (i < n) p[i] = v;
}

// ---------------- weight transpose + hi/lo split: Wt[k][d][c] = split(W[k][c][d]) ----------------
__global__ void wsplit_kernel(const float* __restrict__ W, unsigned short* __restrict__ hi,
                              unsigned short* __restrict__ lo) {
    int i = blockIdx.x * 256 + threadIdx.x;     // over 27*4096
    if (i < 27 * 4096) {
        int k = i >> 12, rem = i & 4095, d = rem >> 6, c = rem & 63;
        float w = W[k * 4096 + c * 64 + d];
        unsigned short h = f2bf(w);
        hi[i] = h;
        lo[i] = f2bf(w - bf2f(h));
    }
}

// ---------------- activation hi/lo split ----------------
__global__ void xsplit_kernel(const float* __restrict__ X, unsigned short* __restrict__ hi,
                              unsigned short* __restrict__ lo, long n) {
    long i = (long)blockIdx.x * 256 + threadIdx.x;
    if (i < n) {
        float x = X[i];
        unsigned short h = f2bf(x);
        hi[i] = h;
        lo[i] = f2bf(x - bf2f(h));
    }
}

// ---------------- MFMA submanifold conv ----------------
// Y[n,d] = sum_k sum_c X[nbr[n,k],c] * W[k,c,d], X given as bf16 hi/lo, W as Wt[k][d][c] hi/lo.
// Block: 128 rows x 64 cols, 4 waves, wave = 32 rows. No LDS, no barriers.
__global__ __launch_bounds__(256) void conv_mfma_kernel(
    const unsigned short* __restrict__ Xhi, const unsigned short* __restrict__ Xlo,
    const int* __restrict__ nbr,
    const unsigned short* __restrict__ Wthi, const unsigned short* __restrict__ Wtlo,
    float* __restrict__ Y, int N)
{
    const int t = threadIdx.x;
    const int wave = t >> 6, lane = t & 63;
    const int m = lane & 15, q = lane >> 4;
    const int qo = q * 8;
    const long base = (long)blockIdx.x * 128 + wave * 32;

    long r0 = base + m;        // rowsub 0 A-row
    long r1 = base + 16 + m;   // rowsub 1 A-row
    long r0c = r0 < N ? r0 : (long)(N - 1);
    long r1c = r1 < N ? r1 : (long)(N - 1);

    v4f acc[2][4];
    #pragma unroll
    for (int s = 0; s < 2; ++s)
        #pragma unroll
        for (int c = 0; c < 4; ++c)
            acc[s][c] = (v4f){0.f, 0.f, 0.f, 0.f};

    for (int k = 0; k < 27; ++k) {
        int j0 = nbr[r0c * 27 + k];
        int j1 = nbr[r1c * 27 + k];
        const unsigned short* x0h = Xhi + (size_t)j0 * 64 + qo;
        const unsigned short* x0l = Xlo + (size_t)j0 * 64 + qo;
        const unsigned short* x1h = Xhi + (size_t)j1 * 64 + qo;
        const unsigned short* x1l = Xlo + (size_t)j1 * 64 + qo;
        v8s a0h0 = *(const v8s*)(x0h);
        v8s a0h1 = *(const v8s*)(x0h + 32);
        v8s a0l0 = *(const v8s*)(x0l);
        v8s a0l1 = *(const v8s*)(x0l + 32);
        v8s a1h0 = *(const v8s*)(x1h);
        v8s a1h1 = *(const v8s*)(x1h + 32);
        v8s a1l0 = *(const v8s*)(x1l);
        v8s a1l1 = *(const v8s*)(x1l + 32);
        const unsigned short* wh = Wthi + (size_t)k * 4096 + m * 64 + qo;
        const unsigned short* wl = Wtlo + (size_t)k * 4096 + m * 64 + qo;
        #pragma unroll
        for (int ct = 0; ct < 4; ++ct) {
            v8s bh0 = *(const v8s*)(wh + ct * 1024);
            v8s bh1 = *(const v8s*)(wh + ct * 1024 + 32);
            v8s bl0 = *(const v8s*)(wl + ct * 1024);
            v8s bl1 = *(const v8s*)(wl + ct * 1024 + 32);
            acc[0][ct] = MFMA16(a0h0, bh0, acc[0][ct], 0, 0, 0);
            acc[0][ct] = MFMA16(a0h1, bh1, acc[0][ct], 0, 0, 0);
            acc[0][ct] = MFMA16(a0l0, bh0, acc[0][ct], 0, 0, 0);
            acc[0][ct] = MFMA16(a0l1, bh1, acc[0][ct], 0, 0, 0);
            acc[0][ct] = MFMA16(a0h0, bl0, acc[0][ct], 0, 0, 0);
            acc[0][ct] = MFMA16(a0h1, bl1, acc[0][ct], 0, 0, 0);
            acc[1][ct] = MFMA16(a1h0, bh0, acc[1][ct], 0, 0, 0);
            acc[1][ct] = MFMA16(a1h1, bh1, acc[1][ct], 0, 0, 0);
            acc[1][ct] = MFMA16(a1l0, bh0, acc[1][ct], 0, 0, 0);
            acc[1][ct] = MFMA16(a1l1, bh1, acc[1][ct], 0, 0, 0);
            acc[1][ct] = MFMA16(a1h0, bl0, acc[1][ct], 0, 0, 0);
            acc[1][ct] = MFMA16(a1h1, bl1, acc[1][ct], 0, 0, 0);
        }
    }
    // C/D layout: col = lane&15, row(within 16) = q*4 + reg
    #pragma unroll
    for (int s = 0; s < 2; ++s)
        #pragma unroll
        for (int ct = 0; ct < 4; ++ct)
            #pragma unroll
            for (int rg = 0; rg < 4; ++rg) {
                long r = base + s * 16 + q * 4 + rg;
                if (r < N) Y[r * 64 + ct * 16 + m] = acc[s][ct][rg];
            }
}

// ---------------- per-column sum / sumsq ----------------
template<int CC>
__global__ __launch_bounds__(256) void colstats_kernel(const float* __restrict__ Y, int N, float* __restrict__ stats) {
    constexpr int RG = 256 / CC;
    const int t = threadIdx.x;
    const int c = t % CC, rg = t / CC;
    float s = 0.f, s2 = 0.f;
    for (long r = (long)blockIdx.x * RG + rg; r < N; r += (long)gridDim.x * RG) {
        float v = Y[r * CC + c];
        s += v; s2 += v * v;
    }
    __shared__ float sh[256], sh2[256];
    sh[t] = s; sh2[t] = s2;
    __syncthreads();
    if (t < CC) {
        #pragma unroll
        for (int g = 1; g < RG; ++g) { s += sh[g * CC + t]; s2 += sh2[g * CC + t]; }
        atomicAdd(&stats[t], s);
        atomicAdd(&stats[CC + t], s2);
    }
}

__global__ void mkscale_kernel(float* __restrict__ stats, const float* __restrict__ g,
                               const float* __restrict__ b, float invN, int CC) {
    int c = threadIdx.x;
    if (c < CC) {
        float mu = stats[c] * invN;
        float var = stats[CC + c] * invN - mu * mu;
        float sc = g[c] * rsqrtf(var + 1e-5f);
        stats[2 * CC + c] = sc;
        stats[3 * CC + c] = b[c] - mu * sc;
    }
}

// MODE: 0 = y*s+sh ; 1 = leaky(y*s+sh) ; 2 = leaky(y*s+sh + res) ; 3 = res2 + leaky(y*s+sh + res)
// PAIR: also emit bf16 hi/lo split of the result (next conv's input)
template<int CC, int MODE, int PAIR>
__global__ __launch_bounds__(256) void apply_bn_kernel(
    const float* __restrict__ Yin, const float* __restrict__ stats,
    const float* __restrict__ res, const float* __restrict__ res2,
    float* __restrict__ out, unsigned short* __restrict__ ohi,
    unsigned short* __restrict__ olo, long n4)
{
    long i = (long)blockIdx.x * 256 + threadIdx.x;
    if (i >= n4) return;
    int c4 = (int)(i % (CC / 4)) * 4;
    float4 y = ((const float4*)Yin)[i];
    float4 sc = *(const float4*)(stats + 2 * CC + c4);
    float4 sf = *(const float4*)(stats + 3 * CC + c4);
    float x0 = y.x * sc.x + sf.x;
    float x1 = y.y * sc.y + sf.y;
    float x2 = y.z * sc.z + sf.z;
    float x3 = y.w * sc.w + sf.w;
    if (MODE >= 2) {
        float4 rr = ((const float4*)res)[i];
        x0 += rr.x; x1 += rr.y; x2 += rr.z; x3 += rr.w;
    }
    if (MODE >= 1) { x0 = lk(x0); x1 = lk(x1); x2 = lk(x2); x3 = lk(x3); }
    if (MODE == 3) {
        float4 rr2 = ((const float4*)res2)[i];
        x0 += rr2.x; x1 += rr2.y; x2 += rr2.z; x3 += rr2.w;
    }
    ((float4*)out)[i] = make_float4(x0, x1, x2, x3);
    if (PAIR) {
        ushort4 h, l;
        h.x = f2bf(x0); l.x = f2bf(x0 - bf2f(h.x));
        h.y = f2bf(x1); l.y = f2bf(x1 - bf2f(h.y));
        h.z = f2bf(x2); l.z = f2bf(x2 - bf2f(h.z));
        h.w = f2bf(x3); l.w = f2bf(x3 - bf2f(h.w));
        *(ushort4*)(ohi + i * 4) = h;
        *(ushort4*)(olo + i * 4) = l;
    }
}

// ---------------- generic tiled GEMM: Y = act(X[N,CIN] @ W[CIN,COUT] + bias) ----------------
template<int CIN, int COUT, int ACT>
__global__ __launch_bounds__(256) void gemm_kernel(
    const float* __restrict__ X, const float* __restrict__ W,
    const float* __restrict__ bias, float* __restrict__ Y, int N)
{
    constexpr int TX = COUT / 4;
    constexpr int TY = 256 / TX;
    constexpr int ROWS = TY * 4;
    constexpr int CHUNK = (CIN < 64) ? CIN : 64;
    constexpr int NCH = CIN / CHUNK;
    __shared__ float XsT[CHUNK][ROWS + 4];
    __shared__ float Ws[CHUNK][COUT + 4];
    const int t = threadIdx.x;
    const int row0 = blockIdx.x * ROWS;
    const int ty = t / TX, tx = t % TX;
    float acc[4][4] = {{0.f}};
    for (int cc = 0; cc < NCH; ++cc) {
        __syncthreads();
        for (int i = t * 4; i < CHUNK * COUT; i += 1024) {
            int c = i / COUT, d = i % COUT;
            *(float4*)&Ws[c][d] = *(const float4*)(W + (size_t)(cc * CHUNK + c) * COUT + d);
        }
        for (int i = t * 4; i < ROWS * CHUNK; i += 1024) {
            int r = i / CHUNK, c0 = i % CHUNK;
            int gr = row0 + r;
            float4 v = make_float4(0.f, 0.f, 0.f, 0.f);
            if (gr < N) v = *(const float4*)(X + (size_t)gr * CIN + cc * CHUNK + c0);
            XsT[c0 + 0][r] = v.x; XsT[c0 + 1][r] = v.y; XsT[c0 + 2][r] = v.z; XsT[c0 + 3][r] = v.w;
        }
        __syncthreads();
        #pragma unroll 8
        for (int c = 0; c < CHUNK; ++c) {
            float4 xv = *(const float4*)&XsT[c][ty * 4];
            float4 wv = *(const float4*)&Ws[c][tx * 4];
            acc[0][0] += xv.x * wv.x; acc[0][1] += xv.x * wv.y; acc[0][2] += xv.x * wv.z; acc[0][3] += xv.x * wv.w;
            acc[1][0] += xv.y * wv.x; acc[1][1] += xv.y * wv.y; acc[1][2] += xv.y * wv.z; acc[1][3] += xv.y * wv.w;
            acc[2][0] += xv.z * wv.x; acc[2][1] += xv.z * wv.y; acc[2][2] += xv.z * wv.z; acc[2][3] += xv.z * wv.w;
            acc[3][0] += xv.w * wv.x; acc[3][1] += xv.w * wv.y; acc[3][2] += xv.w * wv.z; acc[3][3] += xv.w * wv.w;
        }
    }
    float4 bv = *(const float4*)(bias + tx * 4);
    #pragma unroll
    for (int i2 = 0; i2 < 4; ++i2) {
        int gr = row0 + ty * 4 + i2;
        if (gr < N) {
            float o0 = acc[i2][0] + bv.x, o1 = acc[i2][1] + bv.y;
            float o2 = acc[i2][2] + bv.z, o3 = acc[i2][3] + bv.w;
            if (ACT) { o0 = lk(o0); o1 = lk(o1); o2 = lk(o2); o3 = lk(o3); }
            *(float4*)(Y + (size_t)gr * COUT + tx * 4) = make_float4(o0, o1, o2, o3);
        }
    }
}

// ---------------- fused layer_out + scatter-add (fp32) ----------------
__global__ __launch_bounds__(256) void layer_out_fused_kernel(
    const float* __restrict__ iden, const float* __restrict__ h3,
    const int* __restrict__ cil, const int* __restrict__ dsinv,
    const float* __restrict__ Wo1, const float* __restrict__ bo1,
    const float* __restrict__ Wo2, const float* __restrict__ bo2,
    const int* __restrict__ cin,
    float* __restrict__ psum, float* __restrict__ pcnt, int N)
{
    __shared__ float XsT[64][68];
    __shared__ float Ws[64][68];
    const int t = threadIdx.x;
    const int row0 = blockIdx.x * 64;
    const int ty = t >> 4, tx = t & 15;
    const int lr = t >> 2, ls = t & 3;
    const int gr = row0 + lr;
    int v = (gr < N) ? cil[gr] : 0;
    int vds = dsinv[v];
    float acc[4][4] = {{0.f}};
    for (int cc = 0; cc < 2; ++cc) {
        const float* src = (cc == 0) ? (iden + (size_t)v * 64) : (h3 + (size_t)vds * 64);
        const float* xr = src + ls * 16;
        float4 v0 = *(const float4*)(xr);
        float4 v1 = *(const float4*)(xr + 4);
        float4 v2f = *(const float4*)(xr + 8);
        float4 v3 = *(const float4*)(xr + 12);
        const float* Wk = Wo1 + (size_t)cc * 4096;
        float4 w0 = *(const float4*)(Wk + t * 4);
        float4 w1 = *(const float4*)(Wk + t * 4 + 1024);
        float4 w2 = *(const float4*)(Wk + t * 4 + 2048);
        float4 w3 = *(const float4*)(Wk + t * 4 + 3072);
        __syncthreads();
        {
            int i0 = t * 4;
            *(float4*)&Ws[i0 >> 6][i0 & 63] = w0; i0 += 1024;
            *(float4*)&Ws[i0 >> 6][i0 & 63] = w1; i0 += 1024;
            *(float4*)&Ws[i0 >> 6][i0 & 63] = w2; i0 += 1024;
            *(float4*)&Ws[i0 >> 6][i0 & 63] = w3;
        }
        const int cb = ls * 16;
        XsT[cb + 0][lr] = v0.x; XsT[cb + 1][lr] = v0.y; XsT[cb + 2][lr] = v0.z; XsT[cb + 3][lr] = v0.w;
        XsT[cb + 4][lr] = v1.x; XsT[cb + 5][lr] = v1.y; XsT[cb + 6][lr] = v1.z; XsT[cb + 7][lr] = v1.w;
        XsT[cb + 8][lr] = v2f.x; XsT[cb + 9][lr] = v2f.y; XsT[cb + 10][lr] = v2f.z; XsT[cb + 11][lr] = v2f.w;
        XsT[cb + 12][lr] = v3.x; XsT[cb + 13][lr] = v3.y; XsT[cb + 14][lr] = v3.z; XsT[cb + 15][lr] = v3.w;
        __syncthreads();
        #pragma unroll 16
        for (int c = 0; c < 64; ++c) {
            float4 xv = *(const float4*)&XsT[c][ty * 4];
            float4 wv = *(const float4*)&Ws[c][tx * 4];
            acc[0][0] += xv.x * wv.x; acc[0][1] += xv.x * wv.y; acc[0][2] += xv.x * wv.z; acc[0][3] += xv.x * wv.w;
            acc[1][0] += xv.y * wv.x; acc[1][1] += xv.y * wv.y; acc[1][2] += xv.y * wv.z; acc[1][3] += xv.y * wv.w;
            acc[2][0] += xv.z * wv.x; acc[2][1] += xv.z * wv.y; acc[2][2] += xv.z * wv.z; acc[2][3] += xv.z * wv.w;
            acc[3][0] += xv.w * wv.x; acc[3][1] += xv.w * wv.y; acc[3][2] += xv.w * wv.z; acc[3][3] += xv.w * wv.w;
        }
    }
    float4 u0 = *(const float4*)(Wo2 + t * 4);
    float4 u1 = *(const float4*)(Wo2 + t * 4 + 1024);
    float4 u2 = *(const float4*)(Wo2 + t * 4 + 2048);
    float4 u3 = *(const float4*)(Wo2 + t * 4 + 3072);
    float4 b1v = *(const float4*)(bo1 + tx * 4);
    __syncthreads();
    {
        int i0 = t * 4;
        *(float4*)&Ws[i0 >> 6][i0 & 63] = u0; i0 += 1024;
        *(float4*)&Ws[i0 >> 6][i0 & 63] = u1; i0 += 1024;
        *(float4*)&Ws[i0 >> 6][i0 & 63] = u2; i0 += 1024;
        *(float4*)&Ws[i0 >> 6][i0 & 63] = u3;
    }
    #pragma unroll
    for (int i = 0; i < 4; ++i) {
        XsT[tx * 4 + 0][ty * 4 + i] = lk(acc[i][0] + b1v.x);
        XsT[tx * 4 + 1][ty * 4 + i] = lk(acc[i][1] + b1v.y);
        XsT[tx * 4 + 2][ty * 4 + i] = lk(acc[i][2] + b1v.z);
        XsT[tx * 4 + 3][ty * 4 + i] = lk(acc[i][3] + b1v.w);
    }
    __syncthreads();
    float acc2[4][4] = {{0.f}};
    #pragma unroll 16
    for (int c = 0; c < 64; ++c) {
        float4 xv = *(const float4*)&XsT[c][ty * 4];
        float4 wv = *(const float4*)&Ws[c][tx * 4];
        acc2[0][0] += xv.x * wv.x; acc2[0][1] += xv.x * wv.y; acc2[0][2] += xv.x * wv.z; acc2[0][3] += xv.x * wv.w;
        acc2[1][0] += xv.y * wv.x; acc2[1][1] += xv.y * wv.y; acc2[1][2] += xv.y * wv.z; acc2[1][3] += xv.y * wv.w;
        acc2[2][0] += xv.z * wv.x; acc2[2][1] += xv.z * wv.y; acc2[2][2] += xv.z * wv.z; acc2[2][3] += xv.z * wv.w;
        acc2[3][0] += xv.w * wv.x; acc2[3][1] += xv.w * wv.y; acc2[3][2] += xv.w * wv.z; acc2[3][3] += xv.w * wv.w;
    }
    float4 b2v = *(const float4*)(bo2 + tx * 4);
    #pragma unroll
    for (int i2 = 0; i2 < 4; ++i2) {
        int gr2 = row0 + ty * 4 + i2;
        if (gr2 < N) {
            int tg = cin[gr2];
            float* dst = psum + (size_t)tg * 64 + tx * 4;
            atomicAdd(dst + 0, acc2[i2][0] + b2v.x);
            atomicAdd(dst + 1, acc2[i2][1] + b2v.y);
            atomicAdd(dst + 2, acc2[i2][2] + b2v.z);
            atomicAdd(dst + 3, acc2[i2][3] + b2v.w);
            if (tx == 0) atomicAdd(pcnt + tg, 1.0f);
        }
    }
}

// ---------------- scatter add (segment sum) ----------------
__global__ void scatter_add_kernel(const float* __restrict__ X, const int* __restrict__ idx,
                                   float* __restrict__ sum, float* __restrict__ cnt, long N) {
    long i = (long)blockIdx.x * 256 + threadIdx.x;
    if (i < N * 64) {
        long n = i >> 6; int c = (int)(i & 63);
        int tg = idx[n];
        atomicAdd(&sum[(size_t)tg * 64 + c], X[i]);
        if (c == 0) atomicAdd(&cnt[tg], 1.0f);
    }
}

__global__ void divcnt_kernel(float* __restrict__ sum, const float* __restrict__ cnt, long total) {
    long i = (long)blockIdx.x * 256 + threadIdx.x;
    if (i < total) sum[i] /= fmaxf(cnt[i >> 6], 1.0f);
}

__global__ void gather_out_kernel(const float* __restrict__ pf, const int* __restrict__ cin,
                                  float* __restrict__ out, int N) {
    long i = (long)blockIdx.x * 256 + threadIdx.x;
    if (i < (long)N * 16) {
        int p = (int)(i >> 4), q = (int)(i & 15);
        ((float4*)out)[i] = *(const float4*)(pf + (size_t)cin[p] * 64 + q * 4);
    }
}

// ---------------- logit conv: 1 wave per row, lane = channel ----------------
__global__ __launch_bounds__(256) void logit_kernel(
    const float* __restrict__ vp, const int* __restrict__ nbrp,
    const float* __restrict__ Wlog, const float* __restrict__ blog,
    float* __restrict__ out, int N)
{
    __shared__ float Wl[27 * 64];
    const int t = threadIdx.x;
    for (int i = t; i < 1728; i += 256) Wl[i] = Wlog[i];
    __syncthreads();
    const int wave = t >> 6, lane = t & 63;
    for (long row = (long)blockIdx.x * 4 + wave; row < N; row += (long)gridDim.x * 4) {
        float acc = 0.f;
        #pragma unroll
        for (int k = 0; k < 27; ++k) {
            int j = nbrp[row * 27 + k];
            acc += vp[(size_t)j * 64 + lane] * Wl[k * 64 + lane];
        }
        for (int off = 32; off > 0; off >>= 1) acc += __shfl_down(acc, off, 64);
        if (lane == 0) out[row] = acc + blog[0];
    }
}

// ---------------- loss ----------------
__global__ void loss_scatter1_kernel(const int* __restrict__ coors, int* __restrict__ tflag,
                                     int* __restrict__ winner, int N, int NP) {
    int n = blockIdx.x * 256 + threadIdx.x;
    if (n < N) {
        int b = coors[n * 4], x = coors[n * 4 + 1], y = coors[n * 4 + 2], z = coors[n * 4 + 3];
        int flat = ((b * 240 + x) * 180 + y) * 16 + z;
        tflag[flat] = 1;
        if (n < NP) atomicMax(&winner[flat], n);
    }
}

__global__ void loss_scatter2_kernel(const int* __restrict__ coors, const int* __restrict__ winner,
                                     const float* __restrict__ logit, float* __restrict__ xdense, int NP) {
    int n = blockIdx.x * 256 + threadIdx.x;
    if (n < NP) {
        int b = coors[n * 4], x = coors[n * 4 + 1], y = coors[n * 4 + 2], z = coors[n * 4 + 3];
        int flat = ((b * 240 + x) * 180 + y) * 16 + z;
        if (winner[flat] == n) xdense[flat] = logit[n];
    }
}

__global__ void loss_reduce_kernel(const float* __restrict__ xdense, const int* __restrict__ tflag,
                                   float* __restrict__ accum) {
    int i = blockIdx.x * 256 + threadIdx.x;
    float x = xdense[i];
    float tt = (float)tflag[i];
    float term = fmaxf(x, 0.f) - x * tt + log1pf(expf(-fabsf(x)));
    __shared__ float sh[256];
    sh[threadIdx.x] = term;
    __syncthreads();
    for (int s = 128; s > 0; s >>= 1) {
        if (threadIdx.x < s) sh[threadIdx.x] += sh[threadIdx.x + s];
        __syncthreads();
    }
    if (threadIdx.x == 0) atomicAdd(accum, sh[0]);
}

__global__ void loss_final_kernel(const float* __restrict__ accum, float* __restrict__ out) {
    out[0] = accum[0] / (float)NCELL;
}

// ---------------- host orchestration ----------------
extern "C" void kernel_launch(void* const* d_in, const int* in_sizes, int n_in,
                              void* d_out, int out_size, void* d_ws, size_t ws_size,
                              hipStream_t stream)
{
    const float* feats  = (const float*)d_in[0];
    const float* featsp = (const float*)d_in[1];
    const float* Wv11 = (const float*)d_in[2];
    const float* Wv12 = (const float*)d_in[3];
    const float* Wv21 = (const float*)d_in[4];
    const float* Wv22 = (const float*)d_in[5];
    const float* g11 = (const float*)d_in[6];
    const float* g12 = (const float*)d_in[7];
    const float* g21 = (const float*)d_in[8];
    const float* g22 = (const float*)d_in[9];
    const float* b11 = (const float*)d_in[10];
    const float* b12 = (const float*)d_in[11];
    const float* b21 = (const float*)d_in[12];
    const float* b22 = (const float*)d_in[13];
    const float* Wlog = (const float*)d_in[14];
    const float* blog = (const float*)d_in[15];
    const float* Wi  = (const float*)d_in[16];
    const float* bi  = (const float*)d_in[17];
    const float* Wp1 = (const float*)d_in[18];
    const float* bp1 = (const float*)d_in[19];
    const float* gp1 = (const float*)d_in[20];
    const float* bp1n = (const float*)d_in[21];
    const float* Wp2 = (const float*)d_in[22];
    const float* bp2 = (const float*)d_in[23];
    const float* gp2 = (const float*)d_in[24];
    const float* bp2n = (const float*)d_in[25];
    const float* Wp3 = (const float*)d_in[26];
    const float* bp3 = (const float*)d_in[27];
    const float* Wo1 = (const float*)d_in[28];
    const float* bo1 = (const float*)d_in[29];
    const float* Wo2 = (const float*)d_in[30];
    const float* bo2 = (const float*)d_in[31];
    const int* nbr   = (const int*)d_in[32];
    const int* nbrp  = (const int*)d_in[33];
    const int* coors = (const int*)d_in[34];
    const int* cil   = (const int*)d_in[35];
    const int* cin   = (const int*)d_in[36];
    const int* dsinv = (const int*)d_in[37];
    (void)in_sizes; (void)n_in; (void)out_size; (void)ws_size;

    // ---- ws layout (46,952,561 floats ~= 187.8 MB; round 2 proved >=192 MB available) ----
    float* ws = (float*)d_ws;
    float* A     = ws;                  // 16M : conv fp32 out (full & partial) -> identity
    float* H     = ws + 16000000L;      // 16M : X1 fp32 -> feat_sum
    float* Hpf32 = ws + 32000000L;      //  8M : partial X1 residual
    float* psum  = ws + 40000000L;      //  6.4M
    float* pcnt  = ws + 46400000L;      //  0.1M
    unsigned short* wt = (unsigned short*)(ws + 46500000L);  // 8 x 110592 bf16 (442,368 floats)
    float* stats = ws + 46950000L;      //  10 x 256
    float* lacc  = ws + 46952560L;      //  1
    unsigned short* wh11 = wt + 0L * 110592;
    unsigned short* wl11 = wt + 1L * 110592;
    unsigned short* wh12 = wt + 2L * 110592;
    unsigned short* wl12 = wt + 3L * 110592;
    unsigned short* wh21 = wt + 4L * 110592;
    unsigned short* wl21 = wt + 5L * 110592;
    unsigned short* wh22 = wt + 6L * 110592;
    unsigned short* wl22 = wt + 7L * 110592;

    // ---- d_out as scratch (38.4M floats, fully overwritten by final gather) ----
    float* o = (float*)d_out;
    // conv-phase: full-tensor bf16 pairs
    unsigned short* F0h = (unsigned short*)(o);               // 16M bf16
    unsigned short* F0l = (unsigned short*)(o + 8000000L);
    unsigned short* F1h = (unsigned short*)(o + 16000000L);
    unsigned short* F1l = (unsigned short*)(o + 24000000L);
    // partial-phase pairs (after full convs done)
    unsigned short* P0h = (unsigned short*)(o);
    unsigned short* P0l = (unsigned short*)(o + 4000000L);
    unsigned short* P1h = (unsigned short*)(o + 8000000L);
    unsigned short* P1l = (unsigned short*)(o + 12000000L);
    float* Cp = o + 16000000L;          // 8M : Vp fp32 (logit input)
    // loss region (disjoint from pairs)
    float* xdense = o + 32000000L;      // 1.3824M
    int*   tflag  = (int*)(o + 33382400L);
    int*   winner = (int*)(o + 34764800L);
    float* logitb = o + 36147200L;      // 125k
    float* dscnt  = o + 36272200L;      // 100k
    // post-conv phase (pairs dead)
    float* dssum = o;                   // 6.4M
    float* t1b   = o + 6400000L;        // 3.2M
    float* t2b   = o + 9600000L;        // 3.2M
    float* h3b   = o + 12800000L;       // 6.4M (overlaps dead Cp tail: used only after logit)
    float* out = (float*)d_out;

    auto cdiv = [](long a, long b) { return (unsigned)((a + b - 1) / b); };
    dim3 B256(256);

    // ---- inits ----
    fill_u32_kernel<<<cdiv(2561, 256), B256, 0, stream>>>((unsigned*)stats, 0u, 2561);
    fill_u32_kernel<<<cdiv(6500000, 256), B256, 0, stream>>>((unsigned*)psum, 0u, 6500000);
    fill_u32_kernel<<<cdiv(2764800, 256), B256, 0, stream>>>((unsigned*)xdense, 0u, 2764800);   // xdense+tflag
    fill_u32_kernel<<<cdiv(1382400, 256), B256, 0, stream>>>((unsigned*)winner, 0xFFFFFFFFu, 1382400);

    // ---- weight transpose + split ----
    wsplit_kernel<<<432, B256, 0, stream>>>(Wv11, wh11, wl11);
    wsplit_kernel<<<432, B256, 0, stream>>>(Wv12, wh12, wl12);
    wsplit_kernel<<<432, B256, 0, stream>>>(Wv21, wh21, wl21);
    wsplit_kernel<<<432, B256, 0, stream>>>(Wv22, wh22, wl22);

    // ---- full tensor chain ----
    xsplit_kernel<<<cdiv(16000000, 256), B256, 0, stream>>>(feats, F0h, F0l, 16000000L);
    // s0: conv1(F0) -> A ; bn leaky -> A(inplace) + F1
    conv_mfma_kernel<<<cdiv(NVOX, 128), B256, 0, stream>>>(F0h, F0l, nbr, wh11, wl11, A, NVOX);
    colstats_kernel<64><<<256, B256, 0, stream>>>(A, NVOX, stats + 0 * 256);
    mkscale_kernel<<<1, 64, 0, stream>>>(stats + 0 * 256, g11, b11, 1.0f / NVOX, 64);
    apply_bn_kernel<64, 1, 1><<<cdiv(NVOX * 16L, 256), B256, 0, stream>>>(A, stats + 0 * 256, nullptr, nullptr, A, F1h, F1l, NVOX * 16L);
    // s1: conv2(F1) -> A ; bn + res(feats) leaky -> H(=X1) + F0
    conv_mfma_kernel<<<cdiv(NVOX, 128), B256, 0, stream>>>(F1h, F1l, nbr, wh12, wl12, A, NVOX);
    colstats_kernel<64><<<256, B256, 0, stream>>>(A, NVOX, stats + 1 * 256);
    mkscale_kernel<<<1, 64, 0, stream>>>(stats + 1 * 256, g12, b12, 1.0f / NVOX, 64);
    apply_bn_kernel<64, 2, 1><<<cdiv(NVOX * 16L, 256), B256, 0, stream>>>(A, stats + 1 * 256, feats, nullptr, H, F0h, F0l, NVOX * 16L);
    // s2: conv3(F0) -> A ; bn leaky -> A + F1
    conv_mfma_kernel<<<cdiv(NVOX, 128), B256, 0, stream>>>(F0h, F0l, nbr, wh21, wl21, A, NVOX);
    colstats_kernel<64><<<256, B256, 0, stream>>>(A, NVOX, stats + 2 * 256);
    mkscale_kernel<<<1, 64, 0, stream>>>(stats + 2 * 256, g21, b21, 1.0f / NVOX, 64);
    apply_bn_kernel<64, 1, 1><<<cdiv(NVOX * 16L, 256), B256, 0, stream>>>(A, stats + 2 * 256, nullptr, nullptr, A, F1h, F1l, NVOX * 16L);
    // s3: conv4(F1) -> A ; bn + res(X1=H) leaky + feats -> H(=feat_sum)
    conv_mfma_kernel<<<cdiv(NVOX, 128), B256, 0, stream>>>(F1h, F1l, nbr, wh22, wl22, A, NVOX);
    colstats_kernel<64><<<256, B256, 0, stream>>>(A, NVOX, stats + 3 * 256);
    mkscale_kernel<<<1, 64, 0, stream>>>(stats + 3 * 256, g22, b22, 1.0f / NVOX, 64);
    apply_bn_kernel<64, 3, 0><<<cdiv(NVOX * 16L, 256), B256, 0, stream>>>(A, stats + 3 * 256, H, feats, H, nullptr, nullptr, NVOX * 16L);

    // ---- partial tensor chain (same weights) ----
    xsplit_kernel<<<cdiv(8000000, 256), B256, 0, stream>>>(featsp, P0h, P0l, 8000000L);
    conv_mfma_kernel<<<cdiv(NPART, 128), B256, 0, stream>>>(P0h, P0l, nbrp, wh11, wl11, A, NPART);
    colstats_kernel<64><<<256, B256, 0, stream>>>(A, NPART, stats + 4 * 256);
    mkscale_kernel<<<1, 64, 0, stream>>>(stats + 4 * 256, g11, b11, 1.0f / NPART, 64);
    apply_bn_kernel<64, 1, 1><<<cdiv(NPART * 16L, 256), B256, 0, stream>>>(A, stats + 4 * 256, nullptr, nullptr, A, P1h, P1l, NPART * 16L);
    conv_mfma_kernel<<<cdiv(NPART, 128), B256, 0, stream>>>(P1h, P1l, nbrp, wh12, wl12, A, NPART);
    colstats_kernel<64><<<256, B256, 0, stream>>>(A, NPART, stats + 5 * 256);
    mkscale_kernel<<<1, 64, 0, stream>>>(stats + 5 * 256, g12, b12, 1.0f / NPART, 64);
    apply_bn_kernel<64, 2, 1><<<cdiv(NPART * 16L, 256), B256, 0, stream>>>(A, stats + 5 * 256, featsp, nullptr, Hpf32, P0h, P0l, NPART * 16L);
    conv_mfma_kernel<<<cdiv(NPART, 128), B256, 0, stream>>>(P0h, P0l, nbrp, wh21, wl21, A, NPART);
    colstats_kernel<64><<<256, B256, 0, stream>>>(A, NPART, stats + 6 * 256);
    mkscale_kernel<<<1, 64, 0, stream>>>(stats + 6 * 256, g21, b21, 1.0f / NPART, 64);
    apply_bn_kernel<64, 1, 1><<<cdiv(NPART * 16L, 256), B256, 0, stream>>>(A, stats + 6 * 256, nullptr, nullptr, A, P1h, P1l, NPART * 16L);
    conv_mfma_kernel<<<cdiv(NPART, 128), B256, 0, stream>>>(P1h, P1l, nbrp, wh22, wl22, A, NPART);
    colstats_kernel<64><<<256, B256, 0, stream>>>(A, NPART, stats + 7 * 256);
    mkscale_kernel<<<1, 64, 0, stream>>>(stats + 7 * 256, g22, b22, 1.0f / NPART, 64);
    apply_bn_kernel<64, 2, 0><<<cdiv(NPART * 16L, 256), B256, 0, stream>>>(A, stats + 7 * 256, Hpf32, nullptr, Cp, nullptr, nullptr, NPART * 16L);

    // ---- logits + BCE loss ----
    logit_kernel<<<cdiv(NPART, 4), B256, 0, stream>>>(Cp, nbrp, Wlog, blog, logitb, NPART);
    loss_scatter1_kernel<<<cdiv(NVOX, 256), B256, 0, stream>>>(coors, tflag, winner, NVOX, NPART);
    loss_scatter2_kernel<<<cdiv(NPART, 256), B256, 0, stream>>>(coors, winner, logitb, xdense, NPART);
    loss_reduce_kernel<<<NCELL / 256, B256, 0, stream>>>(xdense, tflag, lacc);

    // ---- point encoder (pairs dead; reuse o[0..19.2M)) ----
    fill_u32_kernel<<<cdiv(6400000, 256), B256, 0, stream>>>((unsigned*)dssum, 0u, 6400000);
    fill_u32_kernel<<<cdiv(100000, 256), B256, 0, stream>>>((unsigned*)dscnt, 0u, 100000);
    scatter_add_kernel<<<cdiv((long)NVOX * 64, 256), B256, 0, stream>>>(H, dsinv, dssum, dscnt, (long)NVOX);
    divcnt_kernel<<<cdiv((long)NDS * 64, 256), B256, 0, stream>>>(dssum, dscnt, (long)NDS * 64);
    gemm_kernel<64, 64, 1><<<cdiv(NVOX, 64), B256, 0, stream>>>(H, Wi, bi, A, NVOX);   // A = identity

    gemm_kernel<64, 32, 1><<<cdiv(NDS, 128), B256, 0, stream>>>(dssum, Wp1, bp1, t1b, NDS);
    colstats_kernel<32><<<256, B256, 0, stream>>>(t1b, NDS, stats + 8 * 256);
    mkscale_kernel<<<1, 64, 0, stream>>>(stats + 8 * 256, gp1, bp1n, 1.0f / NDS, 32);
    apply_bn_kernel<32, 0, 0><<<cdiv((long)NDS * 8, 256), B256, 0, stream>>>(t1b, stats + 8 * 256, nullptr, nullptr, t1b, nullptr, nullptr, (long)NDS * 8);

    gemm_kernel<32, 32, 1><<<cdiv(NDS, 128), B256, 0, stream>>>(t1b, Wp2, bp2, t2b, NDS);
    colstats_kernel<32><<<256, B256, 0, stream>>>(t2b, NDS, stats + 9 * 256);
    mkscale_kernel<<<1, 64, 0, stream>>>(stats + 9 * 256, gp2, bp2n, 1.0f / NDS, 32);
    apply_bn_kernel<32, 0, 0><<<cdiv((long)NDS * 8, 256), B256, 0, stream>>>(t2b, stats + 9 * 256, nullptr, nullptr, t2b, nullptr, nullptr, (long)NDS * 8);

    gemm_kernel<32, 64, 1><<<cdiv(NDS, 64), B256, 0, stream>>>(t2b, Wp3, bp3, h3b, NDS);

    // ---- fused layer_out + scatter-mean ----
    layer_out_fused_kernel<<<cdiv(NPTS, 64), B256, 0, stream>>>(A, h3b, cil, dsinv, Wo1, bo1, Wo2, bo2, cin, psum, pcnt, NPTS);
    divcnt_kernel<<<cdiv((long)NNEXT * 64, 256), B256, 0, stream>>>(psum, pcnt, (long)NNEXT * 64);

    // ---- final outputs ----
    gather_out_kernel<<<cdiv((long)NPTS * 16, 256), B256, 0, stream>>>(psum, cin, out, NPTS);
    loss_final_kernel<<<1, 1, 0, stream>>>(lacc, out + 38400000L);
}